// Round 2
// baseline (320.434 us; speedup 1.0000x reference)
//
#include <hip/hip_runtime.h>

typedef __bf16 bf16x8 __attribute__((ext_vector_type(8)));
typedef float f32x4 __attribute__((ext_vector_type(4)));
typedef short s4 __attribute__((ext_vector_type(4)));
typedef unsigned short ush;

#define DEV __device__ __forceinline__

// B=8, D_MODEL=512, D_COND=768, N_HEADS=8, dh=64, L=4096, L_COND=256

DEV ush f2bf(float x){
  union { float f; unsigned u; } v; v.f = x;
  unsigned r = v.u + 0x7FFFu + ((v.u >> 16) & 1u);   // RNE
  return (ush)(r >> 16);
}

DEV void gload_lds16(const ush* g, ush* l){
  __builtin_amdgcn_global_load_lds(
      (const __attribute__((address_space(1))) unsigned int*)g,
      (__attribute__((address_space(3))) unsigned int*)l, 16, 0, 0);
}

// ---------------- prep: image transpose-convert (b,512,4096)f32 -> (b*4096,512)bf16 ----------------
__global__ __launch_bounds__(256) void tc_kernel(const float* __restrict__ img, ush* __restrict__ xT){
  __shared__ float tile[32][33];
  const int b = blockIdx.z;
  const int l0 = blockIdx.x << 5, c0 = blockIdx.y << 5;
  const int tx = threadIdx.x & 31, ty = threadIdx.x >> 5;
  const float* src = img + ((size_t)b*512 + c0)*4096 + l0;
  #pragma unroll
  for (int i = 0; i < 32; i += 8) tile[ty+i][tx] = src[(size_t)(ty+i)*4096 + tx];
  __syncthreads();
  ush* dst = xT + ((size_t)b*4096 + l0)*512 + c0;
  #pragma unroll
  for (int i = 0; i < 32; i += 8) dst[(size_t)(ty+i)*512 + tx] = f2bf(tile[tx][ty+i]);
}

// ---------------- prep: convert cond + 4 weight matrices to bf16 ----------------
__global__ __launch_bounds__(256) void cvt_kernel(const float* c0,const float* c1,const float* c2,
                                                  const float* c3,const float* c4,
                                                  ush* o0, ush* o1, ush* o2, ush* o3, ush* o4){
  const int N0=1572864, N1=262144, N2=393216, N3=393216, N4=262144;
  const int stride = gridDim.x * blockDim.x;
  for (int i = blockIdx.x*blockDim.x + threadIdx.x; i < N0+N1+N2+N3+N4; i += stride){
    int j = i; const float* s; ush* d;
    if (j < N0){ s=c0; d=o0; }
    else { j-=N0; if (j<N1){s=c1;d=o1;}
      else { j-=N1; if (j<N2){s=c2;d=o2;}
        else { j-=N2; if (j<N3){s=c3;d=o3;} else { j-=N3; s=c4; d=o4; } } } }
    d[j] = f2bf(s[j]);
  }
}

// ---------------- shared GEMM core: C(128x128) = A(rowmajor over K) . B^T(rowmajor over K) ----------------
DEV void gemm_core(const ush* __restrict__ Ag, long long a_row0, int lda,
                   const ush* __restrict__ Bg, long long b_row0, int ldb,
                   int K, ush* As, ush* Bs, f32x4 acc[4][4])
{
  const int t = threadIdx.x;
  const int lane = t & 63;
  const int wid = t >> 6, wr = wid >> 1, wc = wid & 1;
  #pragma unroll
  for (int mt=0;mt<4;mt++)
    #pragma unroll
    for (int nt=0;nt<4;nt++) acc[mt][nt] = f32x4{0.f,0.f,0.f,0.f};

  const int nk = K >> 6;
  for (int kt = 0; kt < nk; ++kt){
    const int k0 = kt << 6;
    #pragma unroll
    for (int r = 0; r < 4; ++r){
      int idx = (r<<8) + t;
      int row = idx >> 3, slot = idx & 7;
      gload_lds16(Ag + (a_row0 + row)*(long long)lda + k0 + ((slot ^ (row&7))<<3), As + idx*8);
    }
    #pragma unroll
    for (int r = 0; r < 4; ++r){
      int idx = (r<<8) + t;
      int row = idx >> 3, slot = idx & 7;
      gload_lds16(Bg + (b_row0 + row)*(long long)ldb + k0 + ((slot ^ (row&7))<<3), Bs + idx*8);
    }
    __syncthreads();
    #pragma unroll
    for (int kk = 0; kk < 2; ++kk){
      bf16x8 af[4], bfv[4];
      #pragma unroll
      for (int mt=0;mt<4;mt++){
        int row = (wr<<6) + (mt<<4) + (lane & 15);
        int byte = (row<<7) + (kk<<6) + ((lane>>4)<<4);
        byte ^= (row & 7) << 4;
        af[mt] = *(const bf16x8*)((const char*)As + byte);
      }
      #pragma unroll
      for (int nt=0;nt<4;nt++){
        int row = (wc<<6) + (nt<<4) + (lane & 15);
        int byte = (row<<7) + (kk<<6) + ((lane>>4)<<4);
        byte ^= (row & 7) << 4;
        bfv[nt] = *(const bf16x8*)((const char*)Bs + byte);
      }
      #pragma unroll
      for (int mt=0;mt<4;mt++)
        #pragma unroll
        for (int nt=0;nt<4;nt++)
          acc[mt][nt] = __builtin_amdgcn_mfma_f32_16x16x32_bf16(af[mt], bfv[nt], acc[mt][nt], 0,0,0);
    }
    __syncthreads();
  }
}

// ---------------- Q projection: Q = (xT . Wq^T) * 0.125, written as (b,h,l,dh) bf16 ----------------
__global__ __launch_bounds__(256,2) void qproj_kernel(const ush* __restrict__ xT, const ush* __restrict__ Wqb,
                                                      ush* __restrict__ Qg){
  __shared__ ush As[8192], Bs[8192];
  f32x4 acc[4][4];
  const int nb = blockIdx.x & 3, mb = blockIdx.x >> 2;   // M=32768 (256 mb), N=512 (4 nb)
  gemm_core(xT, (long long)mb*128, 512, Wqb, (long long)nb*128, 512, 512, As, Bs, acc);
  const int lane = threadIdx.x & 63, wid = threadIdx.x >> 6, wr = wid>>1, wc = wid&1;
  #pragma unroll
  for (int mt=0;mt<4;mt++)
    #pragma unroll
    for (int nt=0;nt<4;nt++)
      #pragma unroll
      for (int r=0;r<4;r++){
        int m = mb*128 + (wr<<6) + (mt<<4) + ((lane>>4)<<2) + r;
        int n = (nb<<7) + (wc<<6) + (nt<<4) + (lane&15);
        int bb = m >> 12, l = m & 4095, hh = n >> 6, dh = n & 63;
        Qg[(((size_t)(bb*8 + hh)*4096 + l)<<6) + dh] = f2bf(acc[mt][nt][r] * 0.125f);
      }
}

// ---------------- K/V projection: cond . W^T ; K natural (b,j,512), V transposed (b,h,dh,j) ----------------
__global__ __launch_bounds__(256,2) void kvproj_kernel(const ush* __restrict__ cb, const ush* __restrict__ Wkb,
                                                       const ush* __restrict__ Wvb, ush* __restrict__ Kg,
                                                       ush* __restrict__ Vt){
  __shared__ ush As[8192], Bs[8192];
  f32x4 acc[4][4];
  const int which = blockIdx.z;                            // 0=K, 1=V
  const int nb = blockIdx.x & 3, mb = blockIdx.x >> 2;     // M=2048 (16 mb), N=512 (4 nb)
  gemm_core(cb, (long long)mb*128, 768, which ? Wvb : Wkb, (long long)nb*128, 768, 768, As, Bs, acc);
  const int lane = threadIdx.x & 63, wid = threadIdx.x >> 6, wr = wid>>1, wc = wid&1;
  #pragma unroll
  for (int mt=0;mt<4;mt++)
    #pragma unroll
    for (int nt=0;nt<4;nt++)
      #pragma unroll
      for (int r=0;r<4;r++){
        int m = mb*128 + (wr<<6) + (mt<<4) + ((lane>>4)<<2) + r;
        int n = (nb<<7) + (wc<<6) + (nt<<4) + (lane&15);
        int bb = m >> 8, j = m & 255;
        ush val = f2bf(acc[mt][nt][r]);
        if (!which) Kg[(((size_t)(bb*256 + j))<<9) + n] = val;
        else { int hh = n>>6, dh = n&63; Vt[(((size_t)((bb*8+hh)*64 + dh))<<8) + j] = val; }
      }
}

// ---------------- fused attention (swapped-operand): block = (b,h,256 q), 8 waves x 32 q ----------------
// S = mfma(K,Q) so each lane owns ONE q-column: softmax is lane-local + 2 shfl;
// P quads feed mfma_16x16x16bf16_1k PV directly (no LDS P round-trip).
// LDS: K (256x64, swz) + V^T (64x256, swz) = 64KB -> 2 blocks/CU.
__global__ __launch_bounds__(512,4) void attn_kernel(const ush* __restrict__ Qg, const ush* __restrict__ Kg,
                                                     const ush* __restrict__ Vg, const float* __restrict__ mask,
                                                     ush* __restrict__ Oc){
  extern __shared__ char smem[];
  ush* Ks = (ush*)smem;                  // 32KB: row=key(256) x 128B, swz byte^=(row&7)<<4
  ush* Vs = (ush*)(smem + 32768);        // 32KB: row=dh(64) x 512B,  swz byte^=(row&7)<<4 (within 128B)
  const int t = threadIdx.x, lane = t & 63, wid = t >> 6;
  const int qb = blockIdx.x, h = blockIdx.y, b = blockIdx.z;

  #pragma unroll
  for (int r = 0; r < 4; ++r){
    int idx = (r<<9) + t;
    int j = idx >> 3, slot = idx & 7;
    gload_lds16(Kg + ((size_t)(b*256 + j))*512 + h*64 + ((slot ^ (j&7))<<3), Ks + idx*8);
  }
  #pragma unroll
  for (int r = 0; r < 4; ++r){
    int idx = (r<<9) + t;
    int dh = idx >> 5, slot = idx & 31;
    gload_lds16(Vg + ((size_t)((b*8 + h)*64 + dh))*256 + ((((slot&7) ^ (dh&7)) | (slot&24))<<3), Vs + idx*8);
  }
  __syncthreads();

  const int l15 = lane & 15, kg = lane >> 4;
  const int q0 = qb*256 + wid*32;
  const ush* Qbase = Qg + ((size_t)(b*8 + h)*4096)*64;

  #pragma unroll
  for (int mt = 0; mt < 2; ++mt){
    const int qg = q0 + mt*16 + l15;     // this lane's q (pixel index within b)
    // Q as B-fragment: B[k=dh][col=q], k=(lane>>4)*8+j
    bf16x8 qf0 = *(const bf16x8*)(Qbase + (size_t)qg*64 + (kg<<3));
    bf16x8 qf1 = *(const bf16x8*)(Qbase + (size_t)qg*64 + 32 + (kg<<3));

    f32x4 sacc[16];
    #pragma unroll
    for (int nt=0;nt<16;nt++) sacc[nt] = f32x4{0.f,0.f,0.f,0.f};

    // S[key][q]: lane (q=l15,kg) accumulates keys nt*16 + kg*4 + r
    #pragma unroll
    for (int nt=0;nt<16;++nt){
      int row = (nt<<4) + l15;
      const char* kb = (const char*)Ks + (row<<7);
      int sw = (row&7)<<4;
      bf16x8 kf0 = *(const bf16x8*)(kb + (((kg<<4)      ) ^ sw));
      bf16x8 kf1 = *(const bf16x8*)(kb + (((kg<<4) + 64 ) ^ sw));
      sacc[nt] = __builtin_amdgcn_mfma_f32_16x16x32_bf16(kf0, qf0, sacc[nt], 0,0,0);
      sacc[nt] = __builtin_amdgcn_mfma_f32_16x16x32_bf16(kf1, qf1, sacc[nt], 0,0,0);
    }

    // + mask[b][qg][key]: lane's keys are 4 consecutive -> coalesced float4
    const float* mrow = mask + ((size_t)b*4096 + qg)*256 + (kg<<2);
    #pragma unroll
    for (int nt=0;nt<16;++nt){
      float4 mv = *(const float4*)(mrow + (nt<<4));
      sacc[nt][0] += mv.x; sacc[nt][1] += mv.y; sacc[nt][2] += mv.z; sacc[nt][3] += mv.w;
    }

    // softmax over 256 keys: 64 in-lane + cross-kg (lanes {q,q+16,q+32,q+48})
    float mx = sacc[0][0];
    #pragma unroll
    for (int nt=0;nt<16;++nt)
      #pragma unroll
      for (int r=0;r<4;++r) mx = fmaxf(mx, sacc[nt][r]);
    mx = fmaxf(mx, __shfl_xor(mx, 16, 64));
    mx = fmaxf(mx, __shfl_xor(mx, 32, 64));
    float sm = 0.f;
    #pragma unroll
    for (int nt=0;nt<16;++nt)
      #pragma unroll
      for (int r=0;r<4;++r){
        float p = __expf(sacc[nt][r] - mx);
        sacc[nt][r] = p; sm += p;
      }
    sm += __shfl_xor(sm, 16, 64);
    sm += __shfl_xor(sm, 32, 64);
    const float rl = 1.f / sm;

    // P quads -> 16x16x16 B-fragments (k = kg*4 + j), zero cross-lane traffic
    s4 pf[16];
    #pragma unroll
    for (int nt=0;nt<16;++nt)
      #pragma unroll
      for (int r=0;r<4;++r) pf[nt][r] = (short)f2bf(sacc[nt][r]);

    // O^T[dh][q] = V^T . P : A[row=dh][k=key], k=(lane>>4)*4+j
    f32x4 oacc[4];
    #pragma unroll
    for (int tl=0;tl<4;++tl) oacc[tl] = f32x4{0.f,0.f,0.f,0.f};
    #pragma unroll
    for (int nt=0;nt<16;++nt){
      #pragma unroll
      for (int tl=0;tl<4;++tl){
        int dh = (tl<<4) + l15;
        int off = ((nt<<5) + (kg<<3)) ^ ((dh&7)<<4);
        s4 vf = *(const s4*)((const char*)Vs + (dh<<9) + off);
        oacc[tl] = __builtin_amdgcn_mfma_f32_16x16x16bf16_1k(vf, pf[nt], oacc[tl], 0,0,0);
      }
    }

    // scale by 1/sum (lane-local q) and store 4 consecutive dh as one b64
    #pragma unroll
    for (int tl=0;tl<4;++tl){
      s4 ov;
      #pragma unroll
      for (int r=0;r<4;++r) ov[r] = (short)f2bf(oacc[tl][r] * rl);
      *(s4*)(Oc + (((size_t)b*4096 + qg)<<9) + h*64 + (tl<<4) + (kg<<2)) = ov;
    }
  }
}

// ---------------- output projection: out[b] = Wo . Oc[b]^T + bo  (fp32 out, natural layout) ----------------
__global__ __launch_bounds__(256,2) void oproj_kernel(const ush* __restrict__ Wob, const ush* __restrict__ Oc,
                                                      const float* __restrict__ bo, float* __restrict__ out){
  __shared__ ush As[8192], Bs[8192];
  f32x4 acc[4][4];
  const int bz = blockIdx.z;
  const int mb = blockIdx.x >> 5, nb = blockIdx.x & 31;    // M=512 (4 mb), N=4096 (32 nb)
  gemm_core(Wob, (long long)mb*128, 512, Oc + (size_t)bz*4096*512, (long long)nb*128, 512, 512, As, Bs, acc);
  const int lane = threadIdx.x & 63, wid = threadIdx.x >> 6, wr = wid>>1, wc = wid&1;
  #pragma unroll
  for (int mt=0;mt<4;mt++)
    #pragma unroll
    for (int nt=0;nt<4;nt++){
      #pragma unroll
      for (int r=0;r<4;r++){
        int m = (mb<<7) + (wr<<6) + (mt<<4) + ((lane>>4)<<2) + r;
        int n = (nb<<7) + (wc<<6) + (nt<<4) + (lane&15);
        out[(((size_t)(bz*512 + m))<<12) + n] = acc[mt][nt][r] + bo[m];
      }
    }
}

extern "C" void kernel_launch(void* const* d_in, const int* in_sizes, int n_in,
                              void* d_out, int out_size, void* d_ws, size_t ws_size,
                              hipStream_t stream){
  const float* image = (const float*)d_in[0];
  const float* cond  = (const float*)d_in[1];
  const float* mask  = (const float*)d_in[2];
  const float* Wq    = (const float*)d_in[3];
  const float* Wk    = (const float*)d_in[4];
  const float* Wv    = (const float*)d_in[5];
  const float* Wo    = (const float*)d_in[6];
  const float* bo    = (const float*)d_in[7];
  float* out = (float*)d_out;

  char* ws = (char*)d_ws;
  ush* xT   = (ush*)(ws);                       // 33,554,432 B  (b*4096, 512) bf16
  ush* Oc   = xT;                               // aliased: xT dead after qproj
  ush* Qg   = (ush*)(ws + 33554432);            // 33,554,432 B  (b,h,l,dh) bf16
  ush* cndb = (ush*)(ws + 67108864);            //  3,145,728 B
  ush* Kg   = (ush*)(ws + 70254592);            //  2,097,152 B  (b,j,512)
  ush* Vt   = (ush*)(ws + 72351744);            //  2,097,152 B  (b,h,dh,j)
  ush* Wqb  = (ush*)(ws + 74448896);            //    524,288 B
  ush* Wkb  = (ush*)(ws + 74973184);            //    786,432 B
  ush* Wvb  = (ush*)(ws + 75759616);            //    786,432 B
  ush* Wob  = (ush*)(ws + 76546048);            //    524,288 B

  (void)hipFuncSetAttribute((const void*)attn_kernel,
                            hipFuncAttributeMaxDynamicSharedMemorySize, 65536);

  tc_kernel<<<dim3(128,16,8), 256, 0, stream>>>(image, xT);
  cvt_kernel<<<dim3(1024), 256, 0, stream>>>(cond, Wq, Wk, Wv, Wo, cndb, Wqb, Wkb, Wvb, Wob);
  qproj_kernel<<<dim3(1024), 256, 0, stream>>>(xT, Wqb, Qg);
  kvproj_kernel<<<dim3(64,1,2), 256, 0, stream>>>(cndb, Wkb, Wvb, Kg, Vt);
  attn_kernel<<<dim3(16,8,8), 512, 65536, stream>>>(Qg, Kg, Vt, mask, Oc);
  oproj_kernel<<<dim3(128,1,8), 256, 0, stream>>>(Wob, Oc, bo, out);
}

// Round 3
// 298.154 us; speedup vs baseline: 1.0747x; 1.0747x over previous
//
#include <hip/hip_runtime.h>

typedef __bf16 bf16x8 __attribute__((ext_vector_type(8)));
typedef float f32x4 __attribute__((ext_vector_type(4)));
typedef short s4 __attribute__((ext_vector_type(4)));
typedef unsigned short ush;

#define DEV __device__ __forceinline__

// B=8, D_MODEL=512, D_COND=768, N_HEADS=8, dh=64, L=4096, L_COND=256

DEV ush f2bf(float x){
  union { float f; unsigned u; } v; v.f = x;
  unsigned r = v.u + 0x7FFFu + ((v.u >> 16) & 1u);   // RNE
  return (ush)(r >> 16);
}

DEV void gload_lds16(const ush* g, ush* l){
  __builtin_amdgcn_global_load_lds(
      (const __attribute__((address_space(1))) unsigned int*)g,
      (__attribute__((address_space(3))) unsigned int*)l, 16, 0, 0);
}

// ---------------- prep: image transpose-convert (b,512,4096)f32 -> (b*4096,512)bf16 ----------------
__global__ __launch_bounds__(256) void tc_kernel(const float* __restrict__ img, ush* __restrict__ xT){
  __shared__ float tile[32][33];
  const int b = blockIdx.z;
  const int l0 = blockIdx.x << 5, c0 = blockIdx.y << 5;
  const int tx = threadIdx.x & 31, ty = threadIdx.x >> 5;
  const float* src = img + ((size_t)b*512 + c0)*4096 + l0;
  #pragma unroll
  for (int i = 0; i < 32; i += 8) tile[ty+i][tx] = src[(size_t)(ty+i)*4096 + tx];
  __syncthreads();
  ush* dst = xT + ((size_t)b*4096 + l0)*512 + c0;
  #pragma unroll
  for (int i = 0; i < 32; i += 8) dst[(size_t)(ty+i)*512 + tx] = f2bf(tile[tx][ty+i]);
}

// ---------------- prep: convert cond + 4 weight matrices to bf16 ----------------
__global__ __launch_bounds__(256) void cvt_kernel(const float* c0,const float* c1,const float* c2,
                                                  const float* c3,const float* c4,
                                                  ush* o0, ush* o1, ush* o2, ush* o3, ush* o4){
  const int N0=1572864, N1=262144, N2=393216, N3=393216, N4=262144;
  const int stride = gridDim.x * blockDim.x;
  for (int i = blockIdx.x*blockDim.x + threadIdx.x; i < N0+N1+N2+N3+N4; i += stride){
    int j = i; const float* s; ush* d;
    if (j < N0){ s=c0; d=o0; }
    else { j-=N0; if (j<N1){s=c1;d=o1;}
      else { j-=N1; if (j<N2){s=c2;d=o2;}
        else { j-=N2; if (j<N3){s=c3;d=o3;} else { j-=N3; s=c4; d=o4; } } } }
    d[j] = f2bf(s[j]);
  }
}

// ---------------- shared GEMM core: C(128x128) = A(rowmajor over K) . B^T(rowmajor over K) ----------------
DEV void gemm_core(const ush* __restrict__ Ag, long long a_row0, int lda,
                   const ush* __restrict__ Bg, long long b_row0, int ldb,
                   int K, ush* As, ush* Bs, f32x4 acc[4][4])
{
  const int t = threadIdx.x;
  const int lane = t & 63;
  const int wid = t >> 6, wr = wid >> 1, wc = wid & 1;
  #pragma unroll
  for (int mt=0;mt<4;mt++)
    #pragma unroll
    for (int nt=0;nt<4;nt++) acc[mt][nt] = f32x4{0.f,0.f,0.f,0.f};

  const int nk = K >> 6;
  for (int kt = 0; kt < nk; ++kt){
    const int k0 = kt << 6;
    #pragma unroll
    for (int r = 0; r < 4; ++r){
      int idx = (r<<8) + t;
      int row = idx >> 3, slot = idx & 7;
      gload_lds16(Ag + (a_row0 + row)*(long long)lda + k0 + ((slot ^ (row&7))<<3), As + idx*8);
    }
    #pragma unroll
    for (int r = 0; r < 4; ++r){
      int idx = (r<<8) + t;
      int row = idx >> 3, slot = idx & 7;
      gload_lds16(Bg + (b_row0 + row)*(long long)ldb + k0 + ((slot ^ (row&7))<<3), Bs + idx*8);
    }
    __syncthreads();
    #pragma unroll
    for (int kk = 0; kk < 2; ++kk){
      bf16x8 af[4], bfv[4];
      #pragma unroll
      for (int mt=0;mt<4;mt++){
        int row = (wr<<6) + (mt<<4) + (lane & 15);
        int byte = (row<<7) + (kk<<6) + ((lane>>4)<<4);
        byte ^= (row & 7) << 4;
        af[mt] = *(const bf16x8*)((const char*)As + byte);
      }
      #pragma unroll
      for (int nt=0;nt<4;nt++){
        int row = (wc<<6) + (nt<<4) + (lane & 15);
        int byte = (row<<7) + (kk<<6) + ((lane>>4)<<4);
        byte ^= (row & 7) << 4;
        bfv[nt] = *(const bf16x8*)((const char*)Bs + byte);
      }
      #pragma unroll
      for (int mt=0;mt<4;mt++)
        #pragma unroll
        for (int nt=0;nt<4;nt++)
          acc[mt][nt] = __builtin_amdgcn_mfma_f32_16x16x32_bf16(af[mt], bfv[nt], acc[mt][nt], 0,0,0);
    }
    __syncthreads();
  }
}

// ---------------- Q projection: Q = (xT . Wq^T) * 0.125, written as (b,h,l,dh) bf16 ----------------
__global__ __launch_bounds__(256,2) void qproj_kernel(const ush* __restrict__ xT, const ush* __restrict__ Wqb,
                                                      ush* __restrict__ Qg){
  __shared__ ush As[8192], Bs[8192];
  f32x4 acc[4][4];
  const int nb = blockIdx.x & 3, mb = blockIdx.x >> 2;   // M=32768 (256 mb), N=512 (4 nb)
  gemm_core(xT, (long long)mb*128, 512, Wqb, (long long)nb*128, 512, 512, As, Bs, acc);
  const int lane = threadIdx.x & 63, wid = threadIdx.x >> 6, wr = wid>>1, wc = wid&1;
  #pragma unroll
  for (int mt=0;mt<4;mt++)
    #pragma unroll
    for (int nt=0;nt<4;nt++)
      #pragma unroll
      for (int r=0;r<4;r++){
        int m = mb*128 + (wr<<6) + (mt<<4) + ((lane>>4)<<2) + r;
        int n = (nb<<7) + (wc<<6) + (nt<<4) + (lane&15);
        int bb = m >> 12, l = m & 4095, hh = n >> 6, dh = n & 63;
        Qg[(((size_t)(bb*8 + hh)*4096 + l)<<6) + dh] = f2bf(acc[mt][nt][r] * 0.125f);
      }
}

// ---------------- K/V projection: cond . W^T ; K natural (b,j,512), V transposed (b,h,dh,j) ----------------
__global__ __launch_bounds__(256,2) void kvproj_kernel(const ush* __restrict__ cb, const ush* __restrict__ Wkb,
                                                       const ush* __restrict__ Wvb, ush* __restrict__ Kg,
                                                       ush* __restrict__ Vt){
  __shared__ ush As[8192], Bs[8192];
  f32x4 acc[4][4];
  const int which = blockIdx.z;                            // 0=K, 1=V
  const int nb = blockIdx.x & 3, mb = blockIdx.x >> 2;     // M=2048 (16 mb), N=512 (4 nb)
  gemm_core(cb, (long long)mb*128, 768, which ? Wvb : Wkb, (long long)nb*128, 768, 768, As, Bs, acc);
  const int lane = threadIdx.x & 63, wid = threadIdx.x >> 6, wr = wid>>1, wc = wid&1;
  #pragma unroll
  for (int mt=0;mt<4;mt++)
    #pragma unroll
    for (int nt=0;nt<4;nt++)
      #pragma unroll
      for (int r=0;r<4;r++){
        int m = mb*128 + (wr<<6) + (mt<<4) + ((lane>>4)<<2) + r;
        int n = (nb<<7) + (wc<<6) + (nt<<4) + (lane&15);
        int bb = m >> 8, j = m & 255;
        ush val = f2bf(acc[mt][nt][r]);
        if (!which) Kg[(((size_t)(bb*256 + j))<<9) + n] = val;
        else { int hh = n>>6, dh = n&63; Vt[(((size_t)((bb*8+hh)*64 + dh))<<8) + j] = val; }
      }
}

// ---------------- fused attention (swapped-operand): block = (b,h,256 q), 8 waves x 32 q ----------------
// S = mfma(K,Q): lane owns one q-column -> lane-local softmax; P converted inline per-nt
// (no pf[16] array, no LDS P round-trip). LDS 64KB = K + V^T. launch_bounds(512,2):
// 256-reg cap so NO SPILL (round-2 lesson: (512,4) forced 550MB of scratch traffic).
__global__ __launch_bounds__(512,2) void attn_kernel(const ush* __restrict__ Qg, const ush* __restrict__ Kg,
                                                     const ush* __restrict__ Vg, const float* __restrict__ mask,
                                                     ush* __restrict__ Oc){
  extern __shared__ char smem[];
  ush* Ks = (ush*)smem;                  // 32KB: row=key(256) x 128B, swz byte^=(row&7)<<4
  ush* Vs = (ush*)(smem + 32768);        // 32KB: row=dh(64) x 512B,  swz byte^=(row&7)<<4 (within 128B)
  const int t = threadIdx.x, lane = t & 63, wid = t >> 6;
  const int qb = blockIdx.x, h = blockIdx.y, b = blockIdx.z;

  #pragma unroll
  for (int r = 0; r < 4; ++r){
    int idx = (r<<9) + t;
    int j = idx >> 3, slot = idx & 7;
    gload_lds16(Kg + ((size_t)(b*256 + j))*512 + h*64 + ((slot ^ (j&7))<<3), Ks + idx*8);
  }
  #pragma unroll
  for (int r = 0; r < 4; ++r){
    int idx = (r<<9) + t;
    int dh = idx >> 5, slot = idx & 31;
    gload_lds16(Vg + ((size_t)((b*8 + h)*64 + dh))*256 + ((((slot&7) ^ (dh&7)) | (slot&24))<<3), Vs + idx*8);
  }
  __syncthreads();

  const int l15 = lane & 15, kg = lane >> 4;
  const int q0 = qb*256 + wid*32;
  const ush* Qbase = Qg + ((size_t)(b*8 + h)*4096)*64;

  #pragma unroll 1
  for (int mt = 0; mt < 2; ++mt){
    const int qg = q0 + mt*16 + l15;     // this lane's q (pixel index within b)
    // Q as B-fragment: B[k=dh][col=q], k=(lane>>4)*8+j
    bf16x8 qf0 = *(const bf16x8*)(Qbase + (size_t)qg*64 + (kg<<3));
    bf16x8 qf1 = *(const bf16x8*)(Qbase + (size_t)qg*64 + 32 + (kg<<3));

    f32x4 sacc[16];
    #pragma unroll
    for (int nt=0;nt<16;nt++) sacc[nt] = f32x4{0.f,0.f,0.f,0.f};

    // S[key][q]: lane (q=l15,kg) accumulates keys nt*16 + kg*4 + r
    #pragma unroll
    for (int nt=0;nt<16;++nt){
      int row = (nt<<4) + l15;
      const char* kb = (const char*)Ks + (row<<7);
      int sw = (row&7)<<4;
      bf16x8 kf0 = *(const bf16x8*)(kb + (((kg<<4)      ) ^ sw));
      bf16x8 kf1 = *(const bf16x8*)(kb + (((kg<<4) + 64 ) ^ sw));
      sacc[nt] = __builtin_amdgcn_mfma_f32_16x16x32_bf16(kf0, qf0, sacc[nt], 0,0,0);
      sacc[nt] = __builtin_amdgcn_mfma_f32_16x16x32_bf16(kf1, qf1, sacc[nt], 0,0,0);
    }

    // + mask[b][qg][key]: lane's keys are 4 consecutive -> coalesced float4
    const float* mrow = mask + ((size_t)b*4096 + qg)*256 + (kg<<2);
    #pragma unroll
    for (int nt=0;nt<16;++nt){
      float4 mv = *(const float4*)(mrow + (nt<<4));
      sacc[nt][0] += mv.x; sacc[nt][1] += mv.y; sacc[nt][2] += mv.z; sacc[nt][3] += mv.w;
    }

    // softmax over 256 keys: 64 in-lane + cross-kg (lanes {q,q+16,q+32,q+48})
    float mx = sacc[0][0];
    #pragma unroll
    for (int nt=0;nt<16;++nt)
      #pragma unroll
      for (int r=0;r<4;++r) mx = fmaxf(mx, sacc[nt][r]);
    mx = fmaxf(mx, __shfl_xor(mx, 16, 64));
    mx = fmaxf(mx, __shfl_xor(mx, 32, 64));
    float sm = 0.f;
    #pragma unroll
    for (int nt=0;nt<16;++nt)
      #pragma unroll
      for (int r=0;r<4;++r){
        float p = __expf(sacc[nt][r] - mx);
        sacc[nt][r] = p; sm += p;
      }
    sm += __shfl_xor(sm, 16, 64);
    sm += __shfl_xor(sm, 32, 64);
    const float rl = 1.f / sm;

    // O^T[dh][q] = V^T . P : convert P per-nt inline (k = kg*4 + j), no pf array
    f32x4 oacc[4];
    #pragma unroll
    for (int tl=0;tl<4;++tl) oacc[tl] = f32x4{0.f,0.f,0.f,0.f};
    #pragma unroll
    for (int nt=0;nt<16;++nt){
      s4 pf;
      #pragma unroll
      for (int r=0;r<4;++r) pf[r] = (short)f2bf(sacc[nt][r]);
      #pragma unroll
      for (int tl=0;tl<4;++tl){
        int dh = (tl<<4) + l15;
        int off = ((nt<<5) + (kg<<3)) ^ ((dh&7)<<4);
        s4 vf = *(const s4*)((const char*)Vs + (dh<<9) + off);
        oacc[tl] = __builtin_amdgcn_mfma_f32_16x16x16bf16_1k(vf, pf, oacc[tl], 0,0,0);
      }
    }

    // scale by 1/sum (lane-local q) and store 4 consecutive dh as one b64
    #pragma unroll
    for (int tl=0;tl<4;++tl){
      s4 ov;
      #pragma unroll
      for (int r=0;r<4;++r) ov[r] = (short)f2bf(oacc[tl][r] * rl);
      *(s4*)(Oc + (((size_t)b*4096 + qg)<<9) + h*64 + (tl<<4) + (kg<<2)) = ov;
    }
  }
}

// ---------------- output projection: out[b] = Wo . Oc[b]^T + bo  (fp32 out, natural layout) ----------------
__global__ __launch_bounds__(256,2) void oproj_kernel(const ush* __restrict__ Wob, const ush* __restrict__ Oc,
                                                      const float* __restrict__ bo, float* __restrict__ out){
  __shared__ ush As[8192], Bs[8192];
  f32x4 acc[4][4];
  const int bz = blockIdx.z;
  const int mb = blockIdx.x >> 5, nb = blockIdx.x & 31;    // M=512 (4 mb), N=4096 (32 nb)
  gemm_core(Wob, (long long)mb*128, 512, Oc + (size_t)bz*4096*512, (long long)nb*128, 512, 512, As, Bs, acc);
  const int lane = threadIdx.x & 63, wid = threadIdx.x >> 6, wr = wid>>1, wc = wid&1;
  #pragma unroll
  for (int mt=0;mt<4;mt++)
    #pragma unroll
    for (int nt=0;nt<4;nt++){
      #pragma unroll
      for (int r=0;r<4;r++){
        int m = (mb<<7) + (wr<<6) + (mt<<4) + ((lane>>4)<<2) + r;
        int n = (nb<<7) + (wc<<6) + (nt<<4) + (lane&15);
        out[(((size_t)(bz*512 + m))<<12) + n] = acc[mt][nt][r] + bo[m];
      }
    }
}

extern "C" void kernel_launch(void* const* d_in, const int* in_sizes, int n_in,
                              void* d_out, int out_size, void* d_ws, size_t ws_size,
                              hipStream_t stream){
  const float* image = (const float*)d_in[0];
  const float* cond  = (const float*)d_in[1];
  const float* mask  = (const float*)d_in[2];
  const float* Wq    = (const float*)d_in[3];
  const float* Wk    = (const float*)d_in[4];
  const float* Wv    = (const float*)d_in[5];
  const float* Wo    = (const float*)d_in[6];
  const float* bo    = (const float*)d_in[7];
  float* out = (float*)d_out;

  char* ws = (char*)d_ws;
  ush* xT   = (ush*)(ws);                       // 33,554,432 B  (b*4096, 512) bf16
  ush* Oc   = xT;                               // aliased: xT dead after qproj
  ush* Qg   = (ush*)(ws + 33554432);            // 33,554,432 B  (b,h,l,dh) bf16
  ush* cndb = (ush*)(ws + 67108864);            //  3,145,728 B
  ush* Kg   = (ush*)(ws + 70254592);            //  2,097,152 B  (b,j,512)
  ush* Vt   = (ush*)(ws + 72351744);            //  2,097,152 B  (b,h,dh,j)
  ush* Wqb  = (ush*)(ws + 74448896);            //    524,288 B
  ush* Wkb  = (ush*)(ws + 74973184);            //    786,432 B
  ush* Wvb  = (ush*)(ws + 75759616);            //    786,432 B
  ush* Wob  = (ush*)(ws + 76546048);            //    524,288 B

  (void)hipFuncSetAttribute((const void*)attn_kernel,
                            hipFuncAttributeMaxDynamicSharedMemorySize, 65536);

  tc_kernel<<<dim3(128,16,8), 256, 0, stream>>>(image, xT);
  cvt_kernel<<<dim3(1024), 256, 0, stream>>>(cond, Wq, Wk, Wv, Wo, cndb, Wqb, Wkb, Wvb, Wob);
  qproj_kernel<<<dim3(1024), 256, 0, stream>>>(xT, Wqb, Qg);
  kvproj_kernel<<<dim3(64,1,2), 256, 0, stream>>>(cndb, Wkb, Wvb, Kg, Vt);
  attn_kernel<<<dim3(16,8,8), 512, 65536, stream>>>(Qg, Kg, Vt, mask, Oc);
  oproj_kernel<<<dim3(128,1,8), 256, 0, stream>>>(Wob, Oc, bo, out);
}

// Round 4
// 159.967 us; speedup vs baseline: 2.0031x; 1.8638x over previous
//
#include <hip/hip_runtime.h>

typedef __bf16 bf16x8 __attribute__((ext_vector_type(8)));
typedef float f32x4 __attribute__((ext_vector_type(4)));
typedef short s4 __attribute__((ext_vector_type(4)));
typedef unsigned short ush;

#define DEV __device__ __forceinline__

// B=8, D_MODEL=512, D_COND=768, N_HEADS=8, dh=64, L=4096, L_COND=256

DEV ush f2bf(float x){
  union { float f; unsigned u; } v; v.f = x;
  unsigned r = v.u + 0x7FFFu + ((v.u >> 16) & 1u);   // RNE
  return (ush)(r >> 16);
}

DEV void gload_lds16(const ush* g, ush* l){
  __builtin_amdgcn_global_load_lds(
      (const __attribute__((address_space(1))) unsigned int*)g,
      (__attribute__((address_space(3))) unsigned int*)l, 16, 0, 0);
}

// ---------------- prep: image transpose-convert (b,512,4096)f32 -> (b*4096,512)bf16 ----------------
__global__ __launch_bounds__(256) void tc_kernel(const float* __restrict__ img, ush* __restrict__ xT){
  __shared__ float tile[32][33];
  const int b = blockIdx.z;
  const int l0 = blockIdx.x << 5, c0 = blockIdx.y << 5;
  const int tx = threadIdx.x & 31, ty = threadIdx.x >> 5;
  const float* src = img + ((size_t)b*512 + c0)*4096 + l0;
  #pragma unroll
  for (int i = 0; i < 32; i += 8) tile[ty+i][tx] = src[(size_t)(ty+i)*4096 + tx];
  __syncthreads();
  ush* dst = xT + ((size_t)b*4096 + l0)*512 + c0;
  #pragma unroll
  for (int i = 0; i < 32; i += 8) dst[(size_t)(ty+i)*512 + tx] = f2bf(tile[tx][ty+i]);
}

// ---------------- prep: convert cond + 4 weight matrices to bf16 ----------------
__global__ __launch_bounds__(256) void cvt_kernel(const float* c0,const float* c1,const float* c2,
                                                  const float* c3,const float* c4,
                                                  ush* o0, ush* o1, ush* o2, ush* o3, ush* o4){
  const int N0=1572864, N1=262144, N2=393216, N3=393216, N4=262144;
  const int stride = gridDim.x * blockDim.x;
  for (int i = blockIdx.x*blockDim.x + threadIdx.x; i < N0+N1+N2+N3+N4; i += stride){
    int j = i; const float* s; ush* d;
    if (j < N0){ s=c0; d=o0; }
    else { j-=N0; if (j<N1){s=c1;d=o1;}
      else { j-=N1; if (j<N2){s=c2;d=o2;}
        else { j-=N2; if (j<N3){s=c3;d=o3;} else { j-=N3; s=c4; d=o4; } } } }
    d[j] = f2bf(s[j]);
  }
}

// ---------------- shared GEMM core: C(128x128) = A(rowmajor over K) . B^T(rowmajor over K) ----------------
DEV void gemm_core(const ush* __restrict__ Ag, long long a_row0, int lda,
                   const ush* __restrict__ Bg, long long b_row0, int ldb,
                   int K, ush* As, ush* Bs, f32x4 acc[4][4])
{
  const int t = threadIdx.x;
  const int lane = t & 63;
  const int wid = t >> 6, wr = wid >> 1, wc = wid & 1;
  #pragma unroll
  for (int mt=0;mt<4;mt++)
    #pragma unroll
    for (int nt=0;nt<4;nt++) acc[mt][nt] = f32x4{0.f,0.f,0.f,0.f};

  const int nk = K >> 6;
  for (int kt = 0; kt < nk; ++kt){
    const int k0 = kt << 6;
    #pragma unroll
    for (int r = 0; r < 4; ++r){
      int idx = (r<<8) + t;
      int row = idx >> 3, slot = idx & 7;
      gload_lds16(Ag + (a_row0 + row)*(long long)lda + k0 + ((slot ^ (row&7))<<3), As + idx*8);
    }
    #pragma unroll
    for (int r = 0; r < 4; ++r){
      int idx = (r<<8) + t;
      int row = idx >> 3, slot = idx & 7;
      gload_lds16(Bg + (b_row0 + row)*(long long)ldb + k0 + ((slot ^ (row&7))<<3), Bs + idx*8);
    }
    __syncthreads();
    #pragma unroll
    for (int kk = 0; kk < 2; ++kk){
      bf16x8 af[4], bfv[4];
      #pragma unroll
      for (int mt=0;mt<4;mt++){
        int row = (wr<<6) + (mt<<4) + (lane & 15);
        int byte = (row<<7) + (kk<<6) + ((lane>>4)<<4);
        byte ^= (row & 7) << 4;
        af[mt] = *(const bf16x8*)((const char*)As + byte);
      }
      #pragma unroll
      for (int nt=0;nt<4;nt++){
        int row = (wc<<6) + (nt<<4) + (lane & 15);
        int byte = (row<<7) + (kk<<6) + ((lane>>4)<<4);
        byte ^= (row & 7) << 4;
        bfv[nt] = *(const bf16x8*)((const char*)Bs + byte);
      }
      #pragma unroll
      for (int mt=0;mt<4;mt++)
        #pragma unroll
        for (int nt=0;nt<4;nt++)
          acc[mt][nt] = __builtin_amdgcn_mfma_f32_16x16x32_bf16(af[mt], bfv[nt], acc[mt][nt], 0,0,0);
    }
    __syncthreads();
  }
}

// ---------------- Q projection: Q = (xT . Wq^T) * 0.125, written as (b,h,l,dh) bf16 ----------------
__global__ __launch_bounds__(256,2) void qproj_kernel(const ush* __restrict__ xT, const ush* __restrict__ Wqb,
                                                      ush* __restrict__ Qg){
  __shared__ ush As[8192], Bs[8192];
  f32x4 acc[4][4];
  const int nb = blockIdx.x & 3, mb = blockIdx.x >> 2;   // M=32768 (256 mb), N=512 (4 nb)
  gemm_core(xT, (long long)mb*128, 512, Wqb, (long long)nb*128, 512, 512, As, Bs, acc);
  const int lane = threadIdx.x & 63, wid = threadIdx.x >> 6, wr = wid>>1, wc = wid&1;
  #pragma unroll
  for (int mt=0;mt<4;mt++)
    #pragma unroll
    for (int nt=0;nt<4;nt++)
      #pragma unroll
      for (int r=0;r<4;r++){
        int m = mb*128 + (wr<<6) + (mt<<4) + ((lane>>4)<<2) + r;
        int n = (nb<<7) + (wc<<6) + (nt<<4) + (lane&15);
        int bb = m >> 12, l = m & 4095, hh = n >> 6, dh = n & 63;
        Qg[(((size_t)(bb*8 + hh)*4096 + l)<<6) + dh] = f2bf(acc[mt][nt][r] * 0.125f);
      }
}

// ---------------- K/V projection: cond . W^T ; K natural (b,j,512), V transposed (b,h,dh,j) ----------------
__global__ __launch_bounds__(256,2) void kvproj_kernel(const ush* __restrict__ cb, const ush* __restrict__ Wkb,
                                                       const ush* __restrict__ Wvb, ush* __restrict__ Kg,
                                                       ush* __restrict__ Vt){
  __shared__ ush As[8192], Bs[8192];
  f32x4 acc[4][4];
  const int which = blockIdx.z;                            // 0=K, 1=V
  const int nb = blockIdx.x & 3, mb = blockIdx.x >> 2;     // M=2048 (16 mb), N=512 (4 nb)
  gemm_core(cb, (long long)mb*128, 768, which ? Wvb : Wkb, (long long)nb*128, 768, 768, As, Bs, acc);
  const int lane = threadIdx.x & 63, wid = threadIdx.x >> 6, wr = wid>>1, wc = wid&1;
  #pragma unroll
  for (int mt=0;mt<4;mt++)
    #pragma unroll
    for (int nt=0;nt<4;nt++)
      #pragma unroll
      for (int r=0;r<4;r++){
        int m = mb*128 + (wr<<6) + (mt<<4) + ((lane>>4)<<2) + r;
        int n = (nb<<7) + (wc<<6) + (nt<<4) + (lane&15);
        int bb = m >> 8, j = m & 255;
        ush val = f2bf(acc[mt][nt][r]);
        if (!which) Kg[(((size_t)(bb*256 + j))<<9) + n] = val;
        else { int hh = n>>6, dh = n&63; Vt[(((size_t)((bb*8+hh)*64 + dh))<<8) + j] = val; }
      }
}

// ---------------- fused attention: swapped-operand + flash 2-half split ----------------
// Keys processed in 2 halves of 128 (sacc[8]=32 regs, not 64); exp->cvt->PV fused per
// nt-quad so each sacc dies immediately. Online-softmax rescale between halves (exact).
// sched_barrier(0) between halves stops the scheduler's mass load-hoisting (the r2/r3
// spill cause: hoisted ds_reads blew past the reg cap -> 224MB scratch writes).
__global__ __launch_bounds__(512,2) void attn_kernel(const ush* __restrict__ Qg, const ush* __restrict__ Kg,
                                                     const ush* __restrict__ Vg, const float* __restrict__ mask,
                                                     ush* __restrict__ Oc){
  extern __shared__ char smem[];
  ush* Ks = (ush*)smem;                  // 32KB: row=key(256) x 128B, swz byte^=(row&7)<<4
  ush* Vs = (ush*)(smem + 32768);        // 32KB: row=dh(64) x 512B,  swz byte^=(row&7)<<4 (per 128B)
  const int t = threadIdx.x, lane = t & 63, wid = t >> 6;
  const int qb = blockIdx.x, h = blockIdx.y, b = blockIdx.z;

  #pragma unroll
  for (int r = 0; r < 4; ++r){
    int idx = (r<<9) + t;
    int j = idx >> 3, slot = idx & 7;
    gload_lds16(Kg + ((size_t)(b*256 + j))*512 + h*64 + ((slot ^ (j&7))<<3), Ks + idx*8);
  }
  #pragma unroll
  for (int r = 0; r < 4; ++r){
    int idx = (r<<9) + t;
    int dh = idx >> 5, slot = idx & 31;
    gload_lds16(Vg + ((size_t)((b*8 + h)*64 + dh))*256 + ((((slot&7) ^ (dh&7)) | (slot&24))<<3), Vs + idx*8);
  }
  __syncthreads();

  const int l15 = lane & 15, kg = lane >> 4;
  const int q0 = qb*256 + wid*32;
  const ush* Qbase = Qg + ((size_t)(b*8 + h)*4096)*64;

  #pragma unroll 1
  for (int mt = 0; mt < 2; ++mt){
    const int qg = q0 + mt*16 + l15;     // this lane's q (pixel index within b)
    bf16x8 qf0 = *(const bf16x8*)(Qbase + (size_t)qg*64 + (kg<<3));
    bf16x8 qf1 = *(const bf16x8*)(Qbase + (size_t)qg*64 + 32 + (kg<<3));
    const float* mrow = mask + ((size_t)b*4096 + qg)*256 + (kg<<2);

    f32x4 oacc[4];
    #pragma unroll
    for (int tl=0;tl<4;++tl) oacc[tl] = f32x4{0.f,0.f,0.f,0.f};
    float m_run = 0.f, s_run = 0.f;

    #pragma unroll
    for (int hf = 0; hf < 2; ++hf){
      // ---- QK^T for keys [hf*128, hf*128+128): lane holds keys hf*128 + nt*16 + kg*4 + r
      f32x4 sacc[8];
      #pragma unroll
      for (int nt=0;nt<8;++nt) sacc[nt] = f32x4{0.f,0.f,0.f,0.f};
      #pragma unroll
      for (int nt=0;nt<8;++nt){
        int row = (hf<<7) + (nt<<4) + l15;
        const char* kb = (const char*)Ks + (row<<7);
        int sw = (row&7)<<4;
        bf16x8 kf0 = *(const bf16x8*)(kb + ((kg<<4) ^ sw));
        bf16x8 kf1 = *(const bf16x8*)(kb + (((kg<<4)+64) ^ sw));
        sacc[nt] = __builtin_amdgcn_mfma_f32_16x16x32_bf16(kf0, qf0, sacc[nt], 0,0,0);
        sacc[nt] = __builtin_amdgcn_mfma_f32_16x16x32_bf16(kf1, qf1, sacc[nt], 0,0,0);
      }

      // ---- + mask, and local max over this half
      float mx = -3.0e38f;
      #pragma unroll
      for (int nt=0;nt<8;++nt){
        float4 mv = *(const float4*)(mrow + (hf<<7) + (nt<<4));
        sacc[nt][0] += mv.x; sacc[nt][1] += mv.y; sacc[nt][2] += mv.z; sacc[nt][3] += mv.w;
        #pragma unroll
        for (int r=0;r<4;++r) mx = fmaxf(mx, sacc[nt][r]);
      }
      mx = fmaxf(mx, __shfl_xor(mx, 16, 64));
      mx = fmaxf(mx, __shfl_xor(mx, 32, 64));

      if (hf == 0){
        m_run = mx;
      } else {
        float mnew = fmaxf(m_run, mx);
        float alpha = __expf(m_run - mnew);
        s_run *= alpha;
        #pragma unroll
        for (int tl=0;tl<4;++tl)
          #pragma unroll
          for (int r=0;r<4;++r) oacc[tl][r] *= alpha;
        m_run = mnew;
      }

      // ---- exp -> bf16 -> PV, fused per nt (sacc[nt] dies right here)
      #pragma unroll
      for (int nt=0;nt<8;++nt){
        s4 pf;
        #pragma unroll
        for (int r=0;r<4;++r){
          float p = __expf(sacc[nt][r] - m_run);
          s_run += p;
          pf[r] = (short)f2bf(p);
        }
        #pragma unroll
        for (int tl=0;tl<4;++tl){
          int dr = (tl<<4) + l15;
          int off = ((hf<<8) + (nt<<5) + (kg<<3)) ^ ((dr&7)<<4);
          s4 vf = *(const s4*)((const char*)Vs + (dr<<9) + off);
          oacc[tl] = __builtin_amdgcn_mfma_f32_16x16x16bf16_1k(vf, pf, oacc[tl], 0,0,0);
        }
      }
      __builtin_amdgcn_sched_barrier(0);   // fence: no cross-half load hoisting
    }

    // ---- final 1/sum (cross-kg) and store 4 consecutive dh as one b64
    s_run += __shfl_xor(s_run, 16, 64);
    s_run += __shfl_xor(s_run, 32, 64);
    const float rl = 1.f / s_run;
    #pragma unroll
    for (int tl=0;tl<4;++tl){
      s4 ov;
      #pragma unroll
      for (int r=0;r<4;++r) ov[r] = (short)f2bf(oacc[tl][r] * rl);
      *(s4*)(Oc + (((size_t)b*4096 + qg)<<9) + h*64 + (tl<<4) + (kg<<2)) = ov;
    }
  }
}

// ---------------- output projection: out[b] = Wo . Oc[b]^T + bo  (fp32 out, natural layout) ----------------
__global__ __launch_bounds__(256,2) void oproj_kernel(const ush* __restrict__ Wob, const ush* __restrict__ Oc,
                                                      const float* __restrict__ bo, float* __restrict__ out){
  __shared__ ush As[8192], Bs[8192];
  f32x4 acc[4][4];
  const int bz = blockIdx.z;
  const int mb = blockIdx.x >> 5, nb = blockIdx.x & 31;    // M=512 (4 mb), N=4096 (32 nb)
  gemm_core(Wob, (long long)mb*128, 512, Oc + (size_t)bz*4096*512, (long long)nb*128, 512, 512, As, Bs, acc);
  const int lane = threadIdx.x & 63, wid = threadIdx.x >> 6, wr = wid>>1, wc = wid&1;
  #pragma unroll
  for (int mt=0;mt<4;mt++)
    #pragma unroll
    for (int nt=0;nt<4;nt++){
      #pragma unroll
      for (int r=0;r<4;r++){
        int m = (mb<<7) + (wr<<6) + (mt<<4) + ((lane>>4)<<2) + r;
        int n = (nb<<7) + (wc<<6) + (nt<<4) + (lane&15);
        out[(((size_t)(bz*512 + m))<<12) + n] = acc[mt][nt][r] + bo[m];
      }
    }
}

extern "C" void kernel_launch(void* const* d_in, const int* in_sizes, int n_in,
                              void* d_out, int out_size, void* d_ws, size_t ws_size,
                              hipStream_t stream){
  const float* image = (const float*)d_in[0];
  const float* cond  = (const float*)d_in[1];
  const float* mask  = (const float*)d_in[2];
  const float* Wq    = (const float*)d_in[3];
  const float* Wk    = (const float*)d_in[4];
  const float* Wv    = (const float*)d_in[5];
  const float* Wo    = (const float*)d_in[6];
  const float* bo    = (const float*)d_in[7];
  float* out = (float*)d_out;

  char* ws = (char*)d_ws;
  ush* xT   = (ush*)(ws);                       // 33,554,432 B  (b*4096, 512) bf16
  ush* Oc   = xT;                               // aliased: xT dead after qproj
  ush* Qg   = (ush*)(ws + 33554432);            // 33,554,432 B  (b,h,l,dh) bf16
  ush* cndb = (ush*)(ws + 67108864);            //  3,145,728 B
  ush* Kg   = (ush*)(ws + 70254592);            //  2,097,152 B  (b,j,512)
  ush* Vt   = (ush*)(ws + 72351744);            //  2,097,152 B  (b,h,dh,j)
  ush* Wqb  = (ush*)(ws + 74448896);            //    524,288 B
  ush* Wkb  = (ush*)(ws + 74973184);            //    786,432 B
  ush* Wvb  = (ush*)(ws + 75759616);            //    786,432 B
  ush* Wob  = (ush*)(ws + 76546048);            //    524,288 B

  (void)hipFuncSetAttribute((const void*)attn_kernel,
                            hipFuncAttributeMaxDynamicSharedMemorySize, 65536);

  tc_kernel<<<dim3(128,16,8), 256, 0, stream>>>(image, xT);
  cvt_kernel<<<dim3(1024), 256, 0, stream>>>(cond, Wq, Wk, Wv, Wo, cndb, Wqb, Wkb, Wvb, Wob);
  qproj_kernel<<<dim3(1024), 256, 0, stream>>>(xT, Wqb, Qg);
  kvproj_kernel<<<dim3(64,1,2), 256, 0, stream>>>(cndb, Wkb, Wvb, Kg, Vt);
  attn_kernel<<<dim3(16,8,8), 512, 65536, stream>>>(Qg, Kg, Vt, mask, Oc);
  oproj_kernel<<<dim3(128,1,8), 256, 0, stream>>>(Wob, Oc, bo, out);
}